// Round 13
// baseline (185.088 us; speedup 1.0000x reference)
//
#include <hip/hip_runtime.h>

// YOLOv7 P3 head (stride 8): B=16, A=3, NC=80, H=W=80.
// Input  (b, a*85, h, w) channel-major fp32.
// Output (b, a*h*w, 85)  fp32: [px,py,pw,ph,conf,cls*80].
//
// v14 = v9 (persistent pipelined blocks) + NONTEMPORAL LOADS.
// Regime shift: v11 showed nt loads are the one active lever (63.5->~58us;
// reads no longer thrash L2 against the write stream). Under nt, read
// latency is full-DRAM (~900cy) and Little's law says one outstanding
// 1KB load per wave (VGPR=16 serial chain) supplies ~4.5 TB/s -- right at
// the observed 3.55 TB/s -> read MLP is now plausibly BINDING, where in
// the cached regime it had 3x slack (why v6/v9 were flat then).
// v9's structure provably holds a second 7KB register set in flight
// (VGPR 56): prefetch tile k+1 during tile k's transform/store.
// 768 blocks x 256 threads x 5 tiles; raw s_barrier with lgkmcnt only
// (prefetch stays in flight across barriers); stores cached (2x2 result).

#define A_       3
#define H_       80
#define W_       80
#define CH_      85                 // 5 + 80 classes
#define HW_      (H_ * W_)          // 6400
#define TILEF_   (CH_ * W_)         // 6800 floats per tile (ba,y)
#define QT_      (TILEF_ / 4)       // 1700 f32x4 quads
#define THREADS_ 256
#define NIT_     7                  // ceil(1700/256)
#define GRID_    768                // 3 blocks/CU exactly
#define TPB_     5                  // tiles per block: 768*5 = 3840

typedef float f32x4 __attribute__((ext_vector_type(4)));

__device__ __forceinline__ float fast_sigmoid(float x) {
    return __builtin_amdgcn_rcpf(1.0f + __expf(-x));
}

__global__ __launch_bounds__(THREADS_) void yolo_head_kernel(
    const float* __restrict__ in,
    const float* __restrict__ anchors,
    float* __restrict__ out)
{
    __shared__ float lds[TILEF_];

    const int t = threadIdx.x;

    // Per-thread quad geometry (identical for every tile): i = ch*20 + xq.
    int chv[NIT_], xqv[NIT_];
#pragma unroll
    for (int k = 0; k < NIT_; ++k) {
        int i = k * THREADS_ + t;
        i = (i < QT_) ? i : (QT_ - 1);
        chv[k] = i / 20;
        xqv[k] = i - 20 * chv[k];
    }

    f32x4 v[NIT_], v2[NIT_];

    // Prologue: load tile 0 of this block (nontemporal).
    {
        const int tile = blockIdx.x;
        const int y_   = tile % H_;
        const int ba_  = tile / H_;
        const float* r_ = in + (size_t)(ba_ * CH_) * HW_ + y_ * W_;
#pragma unroll
        for (int k = 0; k < NIT_; ++k)
            v[k] = __builtin_nontemporal_load(
                       (const f32x4*)(r_ + chv[k] * HW_ + 4 * xqv[k]));
    }

    for (int it = 0; it < TPB_; ++it) {
        const int cur = blockIdx.x + it * GRID_;

        // ---- Prefetch next tile into v2 (nontemporal; uniform branch) ----
        if (it < TPB_ - 1) {
            const int nt  = cur + GRID_;
            const int y_  = nt % H_;
            const int ba_ = nt / H_;
            const float* r_ = in + (size_t)(ba_ * CH_) * HW_ + y_ * W_;
#pragma unroll
            for (int k = 0; k < NIT_; ++k)
                v2[k] = __builtin_nontemporal_load(
                            (const f32x4*)(r_ + chv[k] * HW_ + 4 * xqv[k]));
        }
        __builtin_amdgcn_sched_barrier(0);

        // ---- Transform current tile -> LDS transposed [80 x][85 ch] ----
        const int y  = cur % H_;
        const int ba = cur / H_;
        const int a  = ba % A_;
        const float aw = anchors[2 * a];
        const float ah = anchors[2 * a + 1];
        const float fy = (float)y;

#pragma unroll
        for (int k = 0; k < NIT_; ++k) {
            int i = k * THREADS_ + t;
            if (i < QT_) {
                int ch = chv[k];
                int xq = xqv[k];
                f32x4 d = v[k];
                float r[4];
                if (ch >= 4) {
                    r[0] = fast_sigmoid(d.x);
                    r[1] = fast_sigmoid(d.y);
                    r[2] = fast_sigmoid(d.z);
                    r[3] = fast_sigmoid(d.w);
                } else if (ch == 0) {
                    float xg = (float)(4 * xq);
                    r[0] = (fast_sigmoid(d.x) + xg)        * 8.0f;  // px
                    r[1] = (fast_sigmoid(d.y) + xg + 1.0f) * 8.0f;
                    r[2] = (fast_sigmoid(d.z) + xg + 2.0f) * 8.0f;
                    r[3] = (fast_sigmoid(d.w) + xg + 3.0f) * 8.0f;
                } else if (ch == 1) {
                    r[0] = (fast_sigmoid(d.x) + fy) * 8.0f;         // py
                    r[1] = (fast_sigmoid(d.y) + fy) * 8.0f;
                    r[2] = (fast_sigmoid(d.z) + fy) * 8.0f;
                    r[3] = (fast_sigmoid(d.w) + fy) * 8.0f;
                } else {
                    float s = (ch == 2) ? aw : ah;                  // pw / ph
                    r[0] = __expf(fminf(fmaxf(d.x, -16.0f), 16.0f)) * s;
                    r[1] = __expf(fminf(fmaxf(d.y, -16.0f), 16.0f)) * s;
                    r[2] = __expf(fminf(fmaxf(d.z, -16.0f), 16.0f)) * s;
                    r[3] = __expf(fminf(fmaxf(d.w, -16.0f), 16.0f)) * s;
                }
                int base = 4 * xq * CH_ + ch;   // lds[(4*xq+j)*85 + ch]
#pragma unroll
                for (int j = 0; j < 4; ++j)
                    lds[base + j * CH_] = r[j];
            }
        }
        // LDS writes visible; do NOT drain vmcnt (prefetch stays in flight).
        asm volatile("s_waitcnt lgkmcnt(0)" ::: "memory");
        __builtin_amdgcn_s_barrier();

        // ---- Contiguous LDS read -> contiguous cached stores ----
        const f32x4* lds4 = (const f32x4*)lds;
        f32x4 o[NIT_];
#pragma unroll
        for (int k = 0; k < NIT_; ++k) {
            int c = k * THREADS_ + t;
            c = (c < QT_) ? c : (QT_ - 1);
            o[k] = lds4[c];
        }
        // All reads done before next iteration's LDS writes (WAR guard).
        asm volatile("s_waitcnt lgkmcnt(0)" ::: "memory");
        __builtin_amdgcn_s_barrier();
        __builtin_amdgcn_sched_barrier(0);

        f32x4* out4 = (f32x4*)(out + (size_t)cur * TILEF_);
#pragma unroll
        for (int k = 0; k < NIT_; ++k) {
            int c = k * THREADS_ + t;
            if (c < QT_)
                out4[c] = o[k];
        }

        // Rotate prefetched tile into place (compiler's vmcnt wait for v2
        // lands here, after the stores were issued).
#pragma unroll
        for (int k = 0; k < NIT_; ++k)
            v[k] = v2[k];
    }
}

extern "C" void kernel_launch(void* const* d_in, const int* in_sizes, int n_in,
                              void* d_out, int out_size, void* d_ws, size_t ws_size,
                              hipStream_t stream) {
    const float* in      = (const float*)d_in[0];   // (16, 255, 80, 80) fp32
    const float* anchors = (const float*)d_in[1];   // (3, 2) fp32
    float*       out     = (float*)d_out;           // (16, 19200, 85) fp32

    yolo_head_kernel<<<GRID_, THREADS_, 0, stream>>>(in, anchors, out);
}